// Round 1
// baseline (11097.626 us; speedup 1.0000x reference)
//
#include <hip/hip_runtime.h>
#include <hip/hip_bf16.h>
#include <stdint.h>

#define TT 512
#define HD 512
#define BB 32
#define MM (BB*TT)     // 16384 rows (b*T+t)
#define NG 3072        // 2 dirs * 3 gates * 512

typedef short short8 __attribute__((ext_vector_type(8)));
typedef float f32x4 __attribute__((ext_vector_type(4)));
typedef unsigned short u16;
typedef unsigned int u32;

__device__ __forceinline__ u16 f2bf(float f) {
  __hip_bfloat16 h = __float2bfloat16(f);
  union { __hip_bfloat16 h; u16 u; } c; c.h = h; return c.u;
}
__device__ __forceinline__ float bf2f(u16 u) {
  union { u32 i; float f; } c; c.i = ((u32)u) << 16; return c.f;
}
__device__ __forceinline__ float sigmf(float x) {
  return 1.0f / (1.0f + __expf(-x));
}

// ---------------- f32 -> bf16 convert (vectorized, 8 elems/thread) ----------------
__global__ __launch_bounds__(256) void cvt_bf16(const float* __restrict__ in,
                                                u16* __restrict__ out, int n8) {
  int i = blockIdx.x * 256 + threadIdx.x;
  if (i >= n8) return;
  const float4* p = (const float4*)in;
  float4 a = p[2*i], b = p[2*i+1];
  union { short8 v; u16 u[8]; } o;
  o.u[0]=f2bf(a.x); o.u[1]=f2bf(a.y); o.u[2]=f2bf(a.z); o.u[3]=f2bf(a.w);
  o.u[4]=f2bf(b.x); o.u[5]=f2bf(b.y); o.u[6]=f2bf(b.z); o.u[7]=f2bf(b.w);
  ((short8*)out)[i] = o.v;
}

// ---------------- gx GEMM: C[M][3072] = A[M][K] * W[3072][K]^T  (bf16 in, f32/bf16 out)
// 128x128 tile, BK=32, 4 waves (2x2), each wave 64x64 via 4x4 16x16x32 MFMA frags.
// LDS swizzle: off(row,c) = row*64 + ((c ^ ((row>>1)&3))*16), c = 16B chunk in 64B row.
__global__ __launch_bounds__(256) void gemm_gx(const u16* __restrict__ A,
                                               const u16* __restrict__ Bw,
                                               char* __restrict__ gxout,
                                               int K, int gxf32) {
  __shared__ __align__(16) u16 lA[128*32];
  __shared__ __align__(16) u16 lB[128*32];
  const int tid = threadIdx.x;
  const int lane = tid & 63;
  const int wid = tid >> 6;
  const int wr = wid >> 1, wc = wid & 1;
  const int bm = blockIdx.y * 128, bn = blockIdx.x * 128;
  const int col = lane & 15, kg = lane >> 4;

  f32x4 acc[4][4];
#pragma unroll
  for (int m = 0; m < 4; ++m)
#pragma unroll
    for (int n = 0; n < 4; ++n) acc[m][n] = (f32x4){0.f,0.f,0.f,0.f};

  const int nkt = K >> 5;
  for (int kt = 0; kt < nkt; ++kt) {
    short8 ra[2], rb[2];
    const int kb = kt * 32;
#pragma unroll
    for (int p = 0; p < 2; ++p) {
      int id = p*256 + tid;            // 0..511
      int row = id >> 2, c = id & 3;
      ra[p] = *(const short8*)(A  + (size_t)(bm+row)*K + kb + c*8);
      rb[p] = *(const short8*)(Bw + (size_t)(bn+row)*K + kb + c*8);
    }
    __syncthreads();                    // prev step's reads done before overwrite
#pragma unroll
    for (int p = 0; p < 2; ++p) {
      int id = p*256 + tid;
      int row = id >> 2, c = id & 3;
      int off = row*64 + ((c ^ ((row>>1)&3))*16);
      *(short8*)((char*)lA + off) = ra[p];
      *(short8*)((char*)lB + off) = rb[p];
    }
    __syncthreads();
    short8 af[4], bf[4];
#pragma unroll
    for (int m = 0; m < 4; ++m) {
      int row = wr*64 + m*16 + col;
      af[m] = *(short8*)((char*)lA + row*64 + ((kg ^ ((row>>1)&3))*16));
    }
#pragma unroll
    for (int n = 0; n < 4; ++n) {
      int row = wc*64 + n*16 + col;
      bf[n] = *(short8*)((char*)lB + row*64 + ((kg ^ ((row>>1)&3))*16));
    }
#pragma unroll
    for (int m = 0; m < 4; ++m)
#pragma unroll
      for (int n = 0; n < 4; ++n)
        acc[m][n] = __builtin_amdgcn_mfma_f32_16x16x32_bf16(af[m], bf[n], acc[m][n], 0,0,0);
  }
  // epilogue: C layout col=lane&15, row=(lane>>4)*4+reg
#pragma unroll
  for (int m = 0; m < 4; ++m)
#pragma unroll
    for (int n = 0; n < 4; ++n)
#pragma unroll
      for (int r = 0; r < 4; ++r) {
        int rowg = bm + wr*64 + m*16 + kg*4 + r;
        int colg = bn + wc*64 + n*16 + col;
        float v = acc[m][n][r];
        if (gxf32) ((float*)gxout)[(size_t)rowg*NG + colg] = v;
        else       ((u16*)gxout)[(size_t)rowg*NG + colg] = f2bf(v);
      }
}

// ---------------- persistent BiGRU recurrence ----------------
// grid = 64 WGs: dir = wg>>5 (0=fwd,1=bwd), jb = wg&31 -> h columns [jb*16, jb*16+16)
// block = 256 (4 waves). Waves 0..2 = gates r,z,n (MFMA over K=512, N=16, M=32).
// w_hh held in registers as B-fragments. h state f32 in LDS. h broadcast via
// double-buffered global bf16 image + per-dir monotonic atomic barrier.
__global__ __launch_bounds__(256) void bigru_rec(const char* __restrict__ gx,
                                                 const u16* __restrict__ whhb,
                                                 const float* __restrict__ b_ih,
                                                 const float* __restrict__ b_hh,
                                                 char* __restrict__ out,
                                                 u16* __restrict__ himg,   // [2][2][32][512]
                                                 u32* __restrict__ bar,    // per-dir, stride 32
                                                 int gxf32, int outf32) {
  const int wg = blockIdx.x;
  const int dir = wg >> 5;
  const int jb = wg & 31;
  const int tid = threadIdx.x;
  const int lane = tid & 63;
  const int wv = tid >> 6;
  const int col = lane & 15, kg = lane >> 4;

  __shared__ __align__(16) u16 hstage[32*512];   // 32KB, swizzled
  __shared__ float gh[3][32][16];                // MFMA results
  __shared__ __align__(16) float gxl[3][32][16]; // gx (f32 path)
  __shared__ __align__(16) u16 gxl16[3][32][16]; // gx (bf16 path)
  __shared__ float hf[32][16];                   // f32 h state (this WG's slice)
  __shared__ __align__(16) u16 hnew[32][16];     // bf16 h_new staging
  __shared__ float bihs[48], bhhs[48];

  // --- one-time: load w_hh B-fragments into registers (waves 0..2) ---
  short8 bfrag[16];
  if (wv < 3) {
    const u16* wrow = whhb + (size_t)(dir*1536 + wv*512 + jb*16 + col) * 512;
#pragma unroll
    for (int kc = 0; kc < 16; ++kc)
      bfrag[kc] = *(const short8*)(wrow + kc*32 + kg*8);
  }
  if (tid < 48) {
    int g = tid >> 4, j = tid & 15;
    bihs[tid] = b_ih[dir*1536 + g*512 + jb*16 + j];
    bhhs[tid] = b_hh[dir*1536 + g*512 + jb*16 + j];
  }
  for (int p = tid; p < 512; p += 256) hf[p >> 4][p & 15] = 0.f;
  __syncthreads();

  u32* mybar = bar + dir*32;

  for (int t = 0; t < TT; ++t) {
    const int tt = dir ? (TT - 1 - t) : t;
    // --- stage h image (plain global -> swizzled LDS) ---
    const u16* img = himg + ((size_t)dir*2 + (t & 1)) * 32 * 512;
    short8 hreg[8];
#pragma unroll
    for (int p = 0; p < 8; ++p) {
      int id = p*256 + tid;            // 0..2047 chunks of 8 bf16
      int row = id >> 6, c = id & 63;
      hreg[p] = *(const short8*)(img + row*512 + c*8);
    }
#pragma unroll
    for (int p = 0; p < 8; ++p) {
      int id = p*256 + tid;
      int row = id >> 6, c = id & 63;
      *(short8*)((char*)hstage + row*1024 + ((c ^ (row & 7))*16)) = hreg[p];
    }
    // --- stage gx[t] into LDS ---
    if (gxf32) {
      const float* gxf = (const float*)gx;
      {
        int cid = tid;                  // 384 chunks of 4 floats
        int b = cid/12, rem = cid%12, g = rem>>2, q = rem&3;
        float4 v = *(const float4*)(gxf + (size_t)(b*TT+tt)*NG + dir*1536 + g*512 + jb*16 + q*4);
        *(float4*)&gxl[g][b][q*4] = v;
      }
      if (tid < 128) {
        int cid = 256 + tid;
        int b = cid/12, rem = cid%12, g = rem>>2, q = rem&3;
        float4 v = *(const float4*)(gxf + (size_t)(b*TT+tt)*NG + dir*1536 + g*512 + jb*16 + q*4);
        *(float4*)&gxl[g][b][q*4] = v;
      }
    } else {
      if (tid < 192) {
        const u16* gxb = (const u16*)gx;
        int b = tid/6, rem = tid%6, g = rem>>1, hc = rem&1;
        short8 v = *(const short8*)(gxb + (size_t)(b*TT+tt)*NG + dir*1536 + g*512 + jb*16 + hc*8);
        *(short8*)&gxl16[g][b][hc*8] = v;
      }
    }
    __syncthreads();
    // --- MFMA: gh[g][b][j] = sum_k h[b][k] * w_hh[g*512+jglob][k] ---
    if (wv < 3) {
      f32x4 acc0 = (f32x4){0.f,0.f,0.f,0.f};
      f32x4 acc1 = (f32x4){0.f,0.f,0.f,0.f};
      const int r0 = col, r1 = 16 + col;
#pragma unroll
      for (int kc = 0; kc < 16; ++kc) {
        int c = kc*4 + kg;
        short8 a0 = *(short8*)((char*)hstage + r0*1024 + ((c ^ (r0 & 7))*16));
        short8 a1 = *(short8*)((char*)hstage + r1*1024 + ((c ^ (r1 & 7))*16));
        acc0 = __builtin_amdgcn_mfma_f32_16x16x32_bf16(a0, bfrag[kc], acc0, 0,0,0);
        acc1 = __builtin_amdgcn_mfma_f32_16x16x32_bf16(a1, bfrag[kc], acc1, 0,0,0);
      }
#pragma unroll
      for (int r = 0; r < 4; ++r) {
        gh[wv][kg*4 + r][col]      = acc0[r];
        gh[wv][16 + kg*4 + r][col] = acc1[r];
      }
    }
    __syncthreads();
    // --- gates: each thread 2 (b,j) pairs ---
#pragma unroll
    for (int p = 0; p < 2; ++p) {
      int id = p*256 + tid;            // 0..511
      int b = id >> 4, j = id & 15;
      float xr, xz, xn;
      if (gxf32) { xr = gxl[0][b][j]; xz = gxl[1][b][j]; xn = gxl[2][b][j]; }
      else { xr = bf2f(gxl16[0][b][j]); xz = bf2f(gxl16[1][b][j]); xn = bf2f(gxl16[2][b][j]); }
      float r = sigmf(xr + bihs[j]      + gh[0][b][j] + bhhs[j]);
      float z = sigmf(xz + bihs[16 + j] + gh[1][b][j] + bhhs[16 + j]);
      float n = tanhf(xn + bihs[32 + j] + r * (gh[2][b][j] + bhhs[32 + j]));
      float hv = (1.f - z)*n + z*hf[b][j];
      hf[b][j] = hv;
      hnew[b][j] = f2bf(hv);
      size_t oi = (size_t)(b*TT + tt)*1024 + dir*512 + jb*16 + j;
      if (outf32) ((float*)out)[oi] = hv;
      else        ((u16*)out)[oi] = f2bf(hv);
    }
    __syncthreads();
    // --- publish h_new slice to next image (plain layout) ---
    u16* img2 = himg + ((size_t)dir*2 + ((t + 1) & 1)) * 32 * 512;
    if (tid < 64) {
      int row = tid >> 1, half = tid & 1;
      short8 v = *(short8*)&hnew[row][half*8];
      *(short8*)(img2 + row*512 + jb*16 + half*8) = v;
    }
    __threadfence();
    __syncthreads();
    // --- per-direction monotonic barrier (32 WGs) ---
    if (tid == 0) {
      __hip_atomic_fetch_add(mybar, 1u, __ATOMIC_RELEASE, __HIP_MEMORY_SCOPE_AGENT);
      u32 target = (u32)(t + 1) * 32u;
      while (__hip_atomic_load(mybar, __ATOMIC_ACQUIRE, __HIP_MEMORY_SCOPE_AGENT) < target)
        __builtin_amdgcn_s_sleep(1);
    }
    __syncthreads();
  }
}

// ---------------- host ----------------
extern "C" void kernel_launch(void* const* d_in, const int* in_sizes, int n_in,
                              void* d_out, int out_size, void* d_ws, size_t ws_size,
                              hipStream_t stream) {
  (void)in_sizes; (void)n_in; (void)out_size;
  const float* x    = (const float*)d_in[0];
  const float* wih0 = (const float*)d_in[1];
  const float* whh0 = (const float*)d_in[2];
  const float* bih0 = (const float*)d_in[3];
  const float* bhh0 = (const float*)d_in[4];
  const float* wih1 = (const float*)d_in[5];
  const float* whh1 = (const float*)d_in[6];
  const float* bih1 = (const float*)d_in[7];
  const float* bhh1 = (const float*)d_in[8];

  char* ws = (char*)d_ws;
  size_t off = 0;
  auto alloc = [&](size_t bytes) { size_t o = off; off += (bytes + 255) & ~(size_t)255; return o; };
  size_t off_xb   = alloc((size_t)MM * 512 * 2);       // x bf16 [16384][512]
  size_t off_wih0 = alloc((size_t)3072 * 512 * 2);     // [2*1536][512] bf16
  size_t off_wih1 = alloc((size_t)3072 * 1024 * 2);    // [2*1536][1024] bf16
  size_t off_whh0 = alloc((size_t)3072 * 512 * 2);     // [2][1536][512] bf16
  size_t off_whh1 = alloc((size_t)3072 * 512 * 2);
  size_t off_h0   = alloc((size_t)MM * 1024 * 2);      // layer-0 output bf16 [16384][1024]
  size_t off_sync = alloc(131072 + 512);               // h images (128KB) + barriers
  size_t off_gx   = off;                               // gx last: [16384][3072]
  int gxf32 = (ws_size >= off_gx + (size_t)MM * NG * 4) ? 1 : 0;

  u16* xb    = (u16*)(ws + off_xb);
  u16* wih0b = (u16*)(ws + off_wih0);
  u16* wih1b = (u16*)(ws + off_wih1);
  u16* whh0b = (u16*)(ws + off_whh0);
  u16* whh1b = (u16*)(ws + off_whh1);
  u16* h0b   = (u16*)(ws + off_h0);
  u16* himg  = (u16*)(ws + off_sync);
  u32* bar   = (u32*)(ws + off_sync + 131072);
  char* gx   = ws + off_gx;

  // converts
  cvt_bf16<<<4096, 256, 0, stream>>>(x,    xb,    MM*512/8);
  cvt_bf16<<<768,  256, 0, stream>>>(wih0, wih0b, 3072*512/8);
  cvt_bf16<<<1536, 256, 0, stream>>>(wih1, wih1b, 3072*1024/8);
  cvt_bf16<<<768,  256, 0, stream>>>(whh0, whh0b, 3072*512/8);
  cvt_bf16<<<768,  256, 0, stream>>>(whh1, whh1b, 3072*512/8);

  dim3 ggrid(NG/128, MM/128);   // (24, 128)

  // layer 0
  gemm_gx<<<ggrid, 256, 0, stream>>>(xb, wih0b, gx, 512, gxf32);
  hipMemsetAsync(ws + off_sync, 0, 131072 + 512, stream);
  bigru_rec<<<64, 256, 0, stream>>>(gx, whh0b, bih0, bhh0, (char*)h0b, himg, bar, gxf32, 0);

  // layer 1
  gemm_gx<<<ggrid, 256, 0, stream>>>(h0b, wih1b, gx, 1024, gxf32);
  hipMemsetAsync(ws + off_sync, 0, 131072 + 512, stream);
  bigru_rec<<<64, 256, 0, stream>>>(gx, whh1b, bih1, bhh1, (char*)d_out, himg, bar, gxf32, 1);
}

// Round 3
// 9318.125 us; speedup vs baseline: 1.1910x; 1.1910x over previous
//
#include <hip/hip_runtime.h>
#include <hip/hip_bf16.h>
#include <stdint.h>

#define TT 512
#define HD 512
#define BB 32
#define MM (BB*TT)     // 16384 rows (b*T+t)
#define NG 3072        // 2 dirs * 3 gates * 512

typedef short short8 __attribute__((ext_vector_type(8)));
typedef float f32x4 __attribute__((ext_vector_type(4)));
typedef float f32x2 __attribute__((ext_vector_type(2)));
typedef unsigned short u16;
typedef unsigned int u32;

__device__ __forceinline__ u16 f2bf(float f) {
  __hip_bfloat16 h = __float2bfloat16(f);
  union { __hip_bfloat16 h; u16 u; } c; c.h = h; return c.u;
}
__device__ __forceinline__ float bf2f(u16 u) {
  union { u32 i; float f; } c; c.i = ((u32)u) << 16; return c.f;
}
__device__ __forceinline__ float sigmf(float x) {
  return 1.0f / (1.0f + __expf(-x));
}

// ---------------- f32 -> bf16 convert (vectorized, 8 elems/thread) ----------------
__global__ __launch_bounds__(256) void cvt_bf16(const float* __restrict__ in,
                                                u16* __restrict__ out, int n8) {
  int i = blockIdx.x * 256 + threadIdx.x;
  if (i >= n8) return;
  const float4* p = (const float4*)in;
  float4 a = p[2*i], b = p[2*i+1];
  union { short8 v; u16 u[8]; } o;
  o.u[0]=f2bf(a.x); o.u[1]=f2bf(a.y); o.u[2]=f2bf(a.z); o.u[3]=f2bf(a.w);
  o.u[4]=f2bf(b.x); o.u[5]=f2bf(b.y); o.u[6]=f2bf(b.z); o.u[7]=f2bf(b.w);
  ((short8*)out)[i] = o.v;
}

// ---------------- gx GEMM: C[M][3072] = A[M][K] * W[3072][K]^T  (bf16 in, f32/bf16 out)
__global__ __launch_bounds__(256) void gemm_gx(const u16* __restrict__ A,
                                               const u16* __restrict__ Bw,
                                               char* __restrict__ gxout,
                                               int K, int gxf32) {
  __shared__ __align__(16) u16 lA[128*32];
  __shared__ __align__(16) u16 lB[128*32];
  const int tid = threadIdx.x;
  const int lane = tid & 63;
  const int wid = tid >> 6;
  const int wr = wid >> 1, wc = wid & 1;
  const int bm = blockIdx.y * 128, bn = blockIdx.x * 128;
  const int col = lane & 15, kg = lane >> 4;

  f32x4 acc[4][4];
#pragma unroll
  for (int m = 0; m < 4; ++m)
#pragma unroll
    for (int n = 0; n < 4; ++n) acc[m][n] = (f32x4){0.f,0.f,0.f,0.f};

  const int nkt = K >> 5;
  for (int kt = 0; kt < nkt; ++kt) {
    short8 ra[2], rb[2];
    const int kb = kt * 32;
#pragma unroll
    for (int p = 0; p < 2; ++p) {
      int id = p*256 + tid;            // 0..511
      int row = id >> 2, c = id & 3;
      ra[p] = *(const short8*)(A  + (size_t)(bm+row)*K + kb + c*8);
      rb[p] = *(const short8*)(Bw + (size_t)(bn+row)*K + kb + c*8);
    }
    __syncthreads();                    // prev step's reads done before overwrite
#pragma unroll
    for (int p = 0; p < 2; ++p) {
      int id = p*256 + tid;
      int row = id >> 2, c = id & 3;
      int off = row*64 + ((c ^ ((row>>1)&3))*16);
      *(short8*)((char*)lA + off) = ra[p];
      *(short8*)((char*)lB + off) = rb[p];
    }
    __syncthreads();
    short8 af[4], bf[4];
#pragma unroll
    for (int m = 0; m < 4; ++m) {
      int row = wr*64 + m*16 + col;
      af[m] = *(short8*)((char*)lA + row*64 + ((kg ^ ((row>>1)&3))*16));
    }
#pragma unroll
    for (int n = 0; n < 4; ++n) {
      int row = wc*64 + n*16 + col;
      bf[n] = *(short8*)((char*)lB + row*64 + ((kg ^ ((row>>1)&3))*16));
    }
#pragma unroll
    for (int m = 0; m < 4; ++m)
#pragma unroll
      for (int n = 0; n < 4; ++n)
        acc[m][n] = __builtin_amdgcn_mfma_f32_16x16x32_bf16(af[m], bf[n], acc[m][n], 0,0,0);
  }
#pragma unroll
  for (int m = 0; m < 4; ++m)
#pragma unroll
    for (int n = 0; n < 4; ++n)
#pragma unroll
      for (int r = 0; r < 4; ++r) {
        int rowg = bm + wr*64 + m*16 + kg*4 + r;
        int colg = bn + wc*64 + n*16 + col;
        float v = acc[m][n][r];
        if (gxf32) ((float*)gxout)[(size_t)rowg*NG + colg] = v;
        else       ((u16*)gxout)[(size_t)rowg*NG + colg] = f2bf(v);
      }
}

// ---------------- persistent BiGRU recurrence ----------------
// grid = 64 WGs: dir = wg>>5, jb = wg&31 -> h columns [jb*16, jb*16+16).
// Sync: per-(WG,wave) monotonic flags (padded 64B lines). Each wave release-stores
// flag=t+1 after publishing its h_new slice (agent-scope packed stores -> LLC).
// Readers poll all 128 flags of their dir with relaxed agent loads + __all ballot.
__global__ __launch_bounds__(256, 1) void bigru_rec(const char* __restrict__ gx,
                                                    const u16* __restrict__ whhb,
                                                    const float* __restrict__ b_ih,
                                                    const float* __restrict__ b_hh,
                                                    char* __restrict__ out,
                                                    u16* __restrict__ himg,   // [2][2][32][512]
                                                    u32* __restrict__ flags,  // [2][128] stride 16 dwords
                                                    int gxf32, int outf32) {
  const int wg = blockIdx.x;
  const int dir = wg >> 5;
  const int jb = wg & 31;
  const int tid = threadIdx.x;
  const int lane = tid & 63;
  const int wv = tid >> 6;
  const int col = lane & 15, kg = lane >> 4;

  __shared__ __align__(16) u16 hstage[32*512];   // 32KB, swizzled
  __shared__ float gh[3][32][16];                // MFMA results
  __shared__ __align__(16) float gxl[3][32][16]; // gx (f32 path)
  __shared__ __align__(16) u16 gxl16[3][32][16]; // gx (bf16 path)
  __shared__ float bihs[48], bhhs[48];

  // --- one-time: w_hh B-fragments into registers (waves 0..2) ---
  short8 bfrag[16];
  if (wv < 3) {
    const u16* wrow = whhb + (size_t)(dir*1536 + wv*512 + jb*16 + col) * 512;
#pragma unroll
    for (int kc = 0; kc < 16; ++kc)
      bfrag[kc] = *(const short8*)(wrow + kc*32 + kg*8);
  }
  if (tid < 48) {
    int g = tid >> 4, j = tid & 15;
    bihs[tid] = b_ih[dir*1536 + g*512 + jb*16 + j];
    bhhs[tid] = b_hh[dir*1536 + g*512 + jb*16 + j];
  }
  __syncthreads();

  // per-thread h state: b = tid>>3 (0..31), j0 = (tid&7)*2, j1 = j0+1
  const int gb = tid >> 3, gj0 = (tid & 7) * 2;
  float hp0 = 0.f, hp1 = 0.f;

  u32* dirflags = flags + (size_t)dir * 128 * 16;
  u32* myflag = dirflags + (size_t)(jb * 4 + wv) * 16;

  for (int t = 0; t < TT; ++t) {
    const int tt = dir ? (TT - 1 - t) : t;

    // --- prefetch gx[tt] into regs (independent of h; overlaps flag poll) ---
    float4 gpreA, gpreB; short8 gpre16;
    int cA_b=0, cA_g=0, cA_q=0, cB_b=0, cB_g=0, cB_q=0, c16_b=0, c16_g=0, c16_h=0;
    if (gxf32) {
      const float* gxf = (const float*)gx;
      { int cid = tid; cA_b = cid/12; int rem = cid%12; cA_g = rem>>2; cA_q = rem&3;
        gpreA = *(const float4*)(gxf + (size_t)(cA_b*TT+tt)*NG + dir*1536 + cA_g*512 + jb*16 + cA_q*4); }
      if (tid < 128) { int cid = 256 + tid; cB_b = cid/12; int rem = cid%12; cB_g = rem>>2; cB_q = rem&3;
        gpreB = *(const float4*)(gxf + (size_t)(cB_b*TT+tt)*NG + dir*1536 + cB_g*512 + jb*16 + cB_q*4); }
    } else {
      if (tid < 192) {
        const u16* gxb = (const u16*)gx;
        c16_b = tid/6; int rem = tid%6; c16_g = rem>>1; c16_h = rem&1;
        gpre16 = *(const short8*)(gxb + (size_t)(c16_b*TT+tt)*NG + dir*1536 + c16_g*512 + jb*16 + c16_h*8);
      }
    }

    // --- wait for all 128 waves of this dir to have published step-t image ---
    if (t > 0) {
      const u32 need = (u32)t;
      const u32* f0 = dirflags + (size_t)lane * 16;
      const u32* f1 = dirflags + (size_t)(64 + lane) * 16;
      int iter = 0;
      while (iter++ < (1 << 24)) {
        u32 a = __hip_atomic_load(f0, __ATOMIC_RELAXED, __HIP_MEMORY_SCOPE_AGENT);
        u32 b = __hip_atomic_load(f1, __ATOMIC_RELAXED, __HIP_MEMORY_SCOPE_AGENT);
        if (__all((a >= need) && (b >= need))) break;
        __builtin_amdgcn_s_sleep(1);
      }
    }
    __builtin_amdgcn_fence(__ATOMIC_ACQUIRE, "agent");

    // --- read h image (plain loads; L2 was invalidated by fence) ---
    const u16* img = himg + ((size_t)dir*2 + (t & 1)) * 32 * 512;
    short8 hreg[8];
#pragma unroll
    for (int p = 0; p < 8; ++p) {
      int id = p*256 + tid;
      int row = id >> 6, c = id & 63;
      hreg[p] = *(const short8*)(img + row*512 + c*8);
    }
    // stage gx LDS (no dependency on hreg loads)
    if (gxf32) {
      *(float4*)&gxl[cA_g][cA_b][cA_q*4] = gpreA;
      if (tid < 128) *(float4*)&gxl[cB_g][cB_b][cB_q*4] = gpreB;
    } else {
      if (tid < 192) *(short8*)&gxl16[c16_g][c16_b][c16_h*8] = gpre16;
    }
#pragma unroll
    for (int p = 0; p < 8; ++p) {
      int id = p*256 + tid;
      int row = id >> 6, c = id & 63;
      *(short8*)((char*)hstage + row*1024 + ((c ^ (row & 7))*16)) = hreg[p];
    }
    __syncthreads();

    // --- MFMA: gh[g][b][j] = sum_k h[b][k] * w_hh[g*512+jglob][k] ---
    if (wv < 3) {
      f32x4 acc0 = (f32x4){0.f,0.f,0.f,0.f};
      f32x4 acc1 = (f32x4){0.f,0.f,0.f,0.f};
      const int r0 = col, r1 = 16 + col;
#pragma unroll
      for (int kc = 0; kc < 16; ++kc) {
        int c = kc*4 + kg;
        short8 a0 = *(short8*)((char*)hstage + r0*1024 + ((c ^ (r0 & 7))*16));
        short8 a1 = *(short8*)((char*)hstage + r1*1024 + ((c ^ (r1 & 7))*16));
        acc0 = __builtin_amdgcn_mfma_f32_16x16x32_bf16(a0, bfrag[kc], acc0, 0,0,0);
        acc1 = __builtin_amdgcn_mfma_f32_16x16x32_bf16(a1, bfrag[kc], acc1, 0,0,0);
      }
#pragma unroll
      for (int r = 0; r < 4; ++r) {
        gh[wv][kg*4 + r][col]      = acc0[r];
        gh[wv][16 + kg*4 + r][col] = acc1[r];
      }
    }
    __syncthreads();

    // --- gates: thread -> (b=gb, j0=gj0, j1=gj0+1) ---
    {
      float xr0, xz0, xn0, xr1, xz1, xn1;
      if (gxf32) {
        xr0 = gxl[0][gb][gj0];   xz0 = gxl[1][gb][gj0];   xn0 = gxl[2][gb][gj0];
        xr1 = gxl[0][gb][gj0+1]; xz1 = gxl[1][gb][gj0+1]; xn1 = gxl[2][gb][gj0+1];
      } else {
        xr0 = bf2f(gxl16[0][gb][gj0]);   xz0 = bf2f(gxl16[1][gb][gj0]);   xn0 = bf2f(gxl16[2][gb][gj0]);
        xr1 = bf2f(gxl16[0][gb][gj0+1]); xz1 = bf2f(gxl16[1][gb][gj0+1]); xn1 = bf2f(gxl16[2][gb][gj0+1]);
      }
      float r0 = sigmf(xr0 + bihs[gj0]      + gh[0][gb][gj0] + bhhs[gj0]);
      float z0 = sigmf(xz0 + bihs[16+gj0]   + gh[1][gb][gj0] + bhhs[16+gj0]);
      float n0 = tanhf(xn0 + bihs[32+gj0]   + r0*(gh[2][gb][gj0] + bhhs[32+gj0]));
      float hv0 = (1.f - z0)*n0 + z0*hp0;
      float r1 = sigmf(xr1 + bihs[gj0+1]    + gh[0][gb][gj0+1] + bhhs[gj0+1]);
      float z1 = sigmf(xz1 + bihs[16+gj0+1] + gh[1][gb][gj0+1] + bhhs[16+gj0+1]);
      float n1 = tanhf(xn1 + bihs[32+gj0+1] + r1*(gh[2][gb][gj0+1] + bhhs[32+gj0+1]));
      float hv1 = (1.f - z1)*n1 + z1*hp1;
      hp0 = hv0; hp1 = hv1;

      // out store (nontemporal; keeps L2 clean)
      size_t oi = (size_t)(gb*TT + tt)*1024 + dir*512 + jb*16 + gj0;
      if (outf32) {
        f32x2 ov; ov.x = hv0; ov.y = hv1;
        __builtin_nontemporal_store(ov, (f32x2*)((float*)out + oi));
      } else {
        u32 pv = (u32)f2bf(hv0) | ((u32)f2bf(hv1) << 16);
        __builtin_nontemporal_store(pv, (u32*)((u16*)out + oi));
      }

      // publish h_new slice to next image: agent-scope store -> LLC
      u16* img2 = himg + ((size_t)dir*2 + ((t + 1) & 1)) * 32 * 512;
      u32 hv = (u32)f2bf(hv0) | ((u32)f2bf(hv1) << 16);
      __hip_atomic_store((u32*)(img2 + gb*512 + jb*16 + gj0), hv,
                         __ATOMIC_RELAXED, __HIP_MEMORY_SCOPE_AGENT);
    }

    // --- per-wave flag: release-store orders this wave's prior stores (vmcnt drain) ---
    if (lane == 0)
      __hip_atomic_store(myflag, (u32)(t + 1), __ATOMIC_RELEASE, __HIP_MEMORY_SCOPE_AGENT);
    // no trailing __syncthreads: next step's poll covers own WG's waves too
  }
}

// ---------------- host ----------------
extern "C" void kernel_launch(void* const* d_in, const int* in_sizes, int n_in,
                              void* d_out, int out_size, void* d_ws, size_t ws_size,
                              hipStream_t stream) {
  (void)in_sizes; (void)n_in; (void)out_size;
  const float* x    = (const float*)d_in[0];
  const float* wih0 = (const float*)d_in[1];
  const float* whh0 = (const float*)d_in[2];
  const float* bih0 = (const float*)d_in[3];
  const float* bhh0 = (const float*)d_in[4];
  const float* wih1 = (const float*)d_in[5];
  const float* whh1 = (const float*)d_in[6];
  const float* bih1 = (const float*)d_in[7];
  const float* bhh1 = (const float*)d_in[8];

  char* ws = (char*)d_ws;
  size_t off = 0;
  auto alloc = [&](size_t bytes) { size_t o = off; off += (bytes + 255) & ~(size_t)255; return o; };
  size_t off_xb   = alloc((size_t)MM * 512 * 2);       // x bf16
  size_t off_wih0 = alloc((size_t)3072 * 512 * 2);
  size_t off_wih1 = alloc((size_t)3072 * 1024 * 2);
  size_t off_whh0 = alloc((size_t)3072 * 512 * 2);
  size_t off_whh1 = alloc((size_t)3072 * 512 * 2);
  size_t off_h0   = alloc((size_t)MM * 1024 * 2);      // layer-0 output bf16
  size_t off_sync = alloc(131072 + 16384);             // h images (128KB) + flags (16KB)
  size_t off_gx   = off;                               // gx last
  int gxf32 = (ws_size >= off_gx + (size_t)MM * NG * 4) ? 1 : 0;

  u16* xb    = (u16*)(ws + off_xb);
  u16* wih0b = (u16*)(ws + off_wih0);
  u16* wih1b = (u16*)(ws + off_wih1);
  u16* whh0b = (u16*)(ws + off_whh0);
  u16* whh1b = (u16*)(ws + off_whh1);
  u16* h0b   = (u16*)(ws + off_h0);
  u16* himg  = (u16*)(ws + off_sync);
  u32* flags = (u32*)(ws + off_sync + 131072);
  char* gx   = ws + off_gx;

  cvt_bf16<<<4096, 256, 0, stream>>>(x,    xb,    MM*512/8);
  cvt_bf16<<<768,  256, 0, stream>>>(wih0, wih0b, 3072*512/8);
  cvt_bf16<<<1536, 256, 0, stream>>>(wih1, wih1b, 3072*1024/8);
  cvt_bf16<<<768,  256, 0, stream>>>(whh0, whh0b, 3072*512/8);
  cvt_bf16<<<768,  256, 0, stream>>>(whh1, whh1b, 3072*512/8);

  dim3 ggrid(NG/128, MM/128);   // (24, 128)

  // layer 0
  gemm_gx<<<ggrid, 256, 0, stream>>>(xb, wih0b, gx, 512, gxf32);
  (void)hipMemsetAsync(ws + off_sync, 0, 131072 + 16384, stream);
  bigru_rec<<<64, 256, 0, stream>>>(gx, whh0b, bih0, bhh0, (char*)h0b, himg, flags, gxf32, 0);

  // layer 1
  gemm_gx<<<ggrid, 256, 0, stream>>>(h0b, wih1b, gx, 1024, gxf32);
  (void)hipMemsetAsync(ws + off_sync, 0, 131072 + 16384, stream);
  bigru_rec<<<64, 256, 0, stream>>>(gx, whh1b, bih1, bhh1, (char*)d_out, himg, flags, gxf32, 1);
}

// Round 4
// 7258.492 us; speedup vs baseline: 1.5289x; 1.2838x over previous
//
#include <hip/hip_runtime.h>
#include <hip/hip_bf16.h>
#include <stdint.h>

#define TT 512
#define HD 512
#define BB 32
#define MM (BB*TT)     // 16384 rows (b*T+t)
#define NG 3072        // 2 dirs * 3 gates * 512
#define WGD 16         // workgroups per direction
#define CPW 32         // h columns per workgroup

typedef short short8 __attribute__((ext_vector_type(8)));
typedef float f32x4 __attribute__((ext_vector_type(4)));
typedef float f32x2 __attribute__((ext_vector_type(2)));
typedef unsigned short u16;
typedef unsigned int u32;

__device__ __forceinline__ u16 f2bf(float f) {
  __hip_bfloat16 h = __float2bfloat16(f);
  union { __hip_bfloat16 h; u16 u; } c; c.h = h; return c.u;
}
__device__ __forceinline__ float bf2f(u16 u) {
  union { u32 i; float f; } c; c.i = ((u32)u) << 16; return c.f;
}
__device__ __forceinline__ float sigmf(float x) {
  return 1.0f / (1.0f + __expf(-x));
}

// ---------------- f32 -> bf16 convert ----------------
__global__ __launch_bounds__(256) void cvt_bf16(const float* __restrict__ in,
                                                u16* __restrict__ out, int n8) {
  int i = blockIdx.x * 256 + threadIdx.x;
  if (i >= n8) return;
  const float4* p = (const float4*)in;
  float4 a = p[2*i], b = p[2*i+1];
  union { short8 v; u16 u[8]; } o;
  o.u[0]=f2bf(a.x); o.u[1]=f2bf(a.y); o.u[2]=f2bf(a.z); o.u[3]=f2bf(a.w);
  o.u[4]=f2bf(b.x); o.u[5]=f2bf(b.y); o.u[6]=f2bf(b.z); o.u[7]=f2bf(b.w);
  ((short8*)out)[i] = o.v;
}

// ---------------- gx GEMM (unchanged) ----------------
__global__ __launch_bounds__(256) void gemm_gx(const u16* __restrict__ A,
                                               const u16* __restrict__ Bw,
                                               char* __restrict__ gxout,
                                               int K, int gxf32) {
  __shared__ __align__(16) u16 lA[128*32];
  __shared__ __align__(16) u16 lB[128*32];
  const int tid = threadIdx.x;
  const int lane = tid & 63;
  const int wid = tid >> 6;
  const int wr = wid >> 1, wc = wid & 1;
  const int bm = blockIdx.y * 128, bn = blockIdx.x * 128;
  const int col = lane & 15, kg = lane >> 4;

  f32x4 acc[4][4];
#pragma unroll
  for (int m = 0; m < 4; ++m)
#pragma unroll
    for (int n = 0; n < 4; ++n) acc[m][n] = (f32x4){0.f,0.f,0.f,0.f};

  const int nkt = K >> 5;
  for (int kt = 0; kt < nkt; ++kt) {
    short8 ra[2], rb[2];
    const int kb = kt * 32;
#pragma unroll
    for (int p = 0; p < 2; ++p) {
      int id = p*256 + tid;
      int row = id >> 2, c = id & 3;
      ra[p] = *(const short8*)(A  + (size_t)(bm+row)*K + kb + c*8);
      rb[p] = *(const short8*)(Bw + (size_t)(bn+row)*K + kb + c*8);
    }
    __syncthreads();
#pragma unroll
    for (int p = 0; p < 2; ++p) {
      int id = p*256 + tid;
      int row = id >> 2, c = id & 3;
      int off = row*64 + ((c ^ ((row>>1)&3))*16);
      *(short8*)((char*)lA + off) = ra[p];
      *(short8*)((char*)lB + off) = rb[p];
    }
    __syncthreads();
    short8 af[4], bf[4];
#pragma unroll
    for (int m = 0; m < 4; ++m) {
      int row = wr*64 + m*16 + col;
      af[m] = *(short8*)((char*)lA + row*64 + ((kg ^ ((row>>1)&3))*16));
    }
#pragma unroll
    for (int n = 0; n < 4; ++n) {
      int row = wc*64 + n*16 + col;
      bf[n] = *(short8*)((char*)lB + row*64 + ((kg ^ ((row>>1)&3))*16));
    }
#pragma unroll
    for (int m = 0; m < 4; ++m)
#pragma unroll
      for (int n = 0; n < 4; ++n)
        acc[m][n] = __builtin_amdgcn_mfma_f32_16x16x32_bf16(af[m], bf[n], acc[m][n], 0,0,0);
  }
#pragma unroll
  for (int m = 0; m < 4; ++m)
#pragma unroll
    for (int n = 0; n < 4; ++n)
#pragma unroll
      for (int r = 0; r < 4; ++r) {
        int rowg = bm + wr*64 + m*16 + kg*4 + r;
        int colg = bn + wc*64 + n*16 + col;
        float v = acc[m][n][r];
        if (gxf32) ((float*)gxout)[(size_t)rowg*NG + colg] = v;
        else       ((u16*)gxout)[(size_t)rowg*NG + colg] = f2bf(v);
      }
}

// ---------------- persistent BiGRU recurrence ----------------
// grid = 32 WGs (512 thr, 8 waves): dir = wg>>4, jb = wg&15 -> cols [jb*32, jb*32+32).
// No fences: producers publish h via agent-scope u32 stores (-> LLC); consumers read
// the image with agent-scope relaxed u32 loads (bypass stale L2). One flag per WG,
// released after a __syncthreads (whose waitcnt drains all waves' publish stores).
// Wave 0 alone polls the 16 producer flags.
__global__ __launch_bounds__(512, 2) void bigru_rec(const char* __restrict__ gx,
                                                    const u16* __restrict__ whhb,
                                                    const float* __restrict__ b_ih,
                                                    const float* __restrict__ b_hh,
                                                    char* __restrict__ out,
                                                    u16* __restrict__ himg,   // [2][2][32][512]
                                                    u32* __restrict__ flags,  // [2][16] stride 16 dwords
                                                    int gxf32, int outf32) {
  const int wg = blockIdx.x;
  const int dir = wg >> 4;
  const int jb = wg & 15;
  const int tid = threadIdx.x;
  const int lane = tid & 63;
  const int wv = tid >> 6;
  const int col = lane & 15, kg = lane >> 4;

  __shared__ __align__(16) u16 hstage[32*512];     // 32 KB, swizzled
  __shared__ float gh[3][32][32];                  // 12 KB
  __shared__ __align__(16) float gxl[3][32][32];   // 12 KB (f32 path)
  __shared__ __align__(16) u16 gxl16[3][32][32];   // 6 KB (bf16 path)
  __shared__ float bihs[96], bhhs[96];

  // --- one-time: w_hh B-fragments into registers (waves 0..5: g = wv>>1, ch = wv&1) ---
  short8 bfrag[16];
  if (wv < 6) {
    const int g = wv >> 1, ch = wv & 1;
    const u16* wrow = whhb + (size_t)(dir*1536 + g*512 + jb*CPW + ch*16 + col) * 512;
#pragma unroll
    for (int kc = 0; kc < 16; ++kc)
      bfrag[kc] = *(const short8*)(wrow + kc*32 + kg*8);
  }
  if (tid < 96) {
    int g = tid >> 5, j = tid & 31;
    bihs[tid] = b_ih[dir*1536 + g*512 + jb*CPW + j];
    bhhs[tid] = b_hh[dir*1536 + g*512 + jb*CPW + j];
  }
  __syncthreads();

  // per-thread gate ownership: batch gb, cols (gj0, gj0+1)
  const int gb = tid >> 4, gj0 = (tid & 15) * 2;
  float hp0 = 0.f, hp1 = 0.f;

  u32* dirflags = flags + (size_t)dir * WGD * 16;
  u32* myflag = dirflags + (size_t)jb * 16;

  for (int t = 0; t < TT; ++t) {
    const int tt = dir ? (TT - 1 - t) : t;

    // --- stage gx[tt] -> LDS immediately (L2 stays warm: no invalidations anywhere) ---
    if (gxf32) {
      const float* gxf = (const float*)gx;
      { int cid = tid; int b = cid/24, rem = cid%24, g = rem>>3, q = rem&7;
        float4 v = *(const float4*)(gxf + (size_t)(b*TT+tt)*NG + dir*1536 + g*512 + jb*CPW + q*4);
        *(float4*)&gxl[g][b][q*4] = v; }
      if (tid < 256) {
        int cid = 512 + tid; int b = cid/24, rem = cid%24, g = rem>>3, q = rem&7;
        float4 v = *(const float4*)(gxf + (size_t)(b*TT+tt)*NG + dir*1536 + g*512 + jb*CPW + q*4);
        *(float4*)&gxl[g][b][q*4] = v; }
    } else {
      if (tid < 384) {
        const u16* gxb = (const u16*)gx;
        int b = tid/12, rem = tid%12, g = rem>>2, q = rem&3;
        short8 v = *(const short8*)(gxb + (size_t)(b*TT+tt)*NG + dir*1536 + g*512 + jb*CPW + q*8);
        *(short8*)&gxl16[g][b][q*8] = v;
      }
    }

    // --- wave 0 polls the 16 producer flags of this dir ---
    if (t > 0 && wv == 0) {
      const u32 need = (u32)t;
      const u32* fp = dirflags + (size_t)lane * 16;
      int iter = 0;
      while (iter++ < (1 << 24)) {
        u32 v = (lane < WGD)
              ? __hip_atomic_load(fp, __ATOMIC_RELAXED, __HIP_MEMORY_SCOPE_AGENT)
              : need;
        if (__all(v >= need)) break;
        __builtin_amdgcn_s_sleep(1);
      }
    }
    asm volatile("" ::: "memory");
    __syncthreads();   // (A) flags seen; gh/gxl of prev step fully consumed

    // --- read h image via agent-scope bypass loads -> swizzled LDS ---
    const u32* imgr = (const u32*)(himg + ((size_t)dir*2 + (t & 1)) * 32 * 512);
#pragma unroll
    for (int p = 0; p < 16; ++p) {
      int id = p*512 + tid;            // 8192 u32 = 32 rows x 256
      int row = id >> 8, dcol = id & 255;
      u32 hv = __hip_atomic_load(imgr + row*256 + dcol, __ATOMIC_RELAXED, __HIP_MEMORY_SCOPE_AGENT);
      int c = dcol >> 2;
      *(u32*)((char*)hstage + row*1024 + (((c ^ (row & 7)) << 4) | ((dcol & 3) << 2))) = hv;
    }
    __syncthreads();   // (B)

    // --- MFMA: gh[g][b][jloc] over K=512 (waves 0..5) ---
    if (wv < 6) {
      const int g = wv >> 1, ch = wv & 1;
      f32x4 acc0 = (f32x4){0.f,0.f,0.f,0.f};
      f32x4 acc1 = (f32x4){0.f,0.f,0.f,0.f};
#pragma unroll
      for (int kc = 0; kc < 16; ++kc) {
        int c = kc*4 + kg;
        short8 a0 = *(short8*)((char*)hstage + col*1024       + ((c ^ (col & 7)) << 4));
        short8 a1 = *(short8*)((char*)hstage + (16+col)*1024  + ((c ^ (col & 7)) << 4));
        acc0 = __builtin_amdgcn_mfma_f32_16x16x32_bf16(a0, bfrag[kc], acc0, 0,0,0);
        acc1 = __builtin_amdgcn_mfma_f32_16x16x32_bf16(a1, bfrag[kc], acc1, 0,0,0);
      }
#pragma unroll
      for (int r = 0; r < 4; ++r) {
        gh[g][kg*4 + r][ch*16 + col]      = acc0[r];
        gh[g][16 + kg*4 + r][ch*16 + col] = acc1[r];
      }
    }
    __syncthreads();   // (C)

    // --- gates ---
    float hv0, hv1; u32 pv;
    {
      float xr0, xz0, xn0, xr1, xz1, xn1;
      if (gxf32) {
        xr0 = gxl[0][gb][gj0];   xz0 = gxl[1][gb][gj0];   xn0 = gxl[2][gb][gj0];
        xr1 = gxl[0][gb][gj0+1]; xz1 = gxl[1][gb][gj0+1]; xn1 = gxl[2][gb][gj0+1];
      } else {
        xr0 = bf2f(gxl16[0][gb][gj0]);   xz0 = bf2f(gxl16[1][gb][gj0]);   xn0 = bf2f(gxl16[2][gb][gj0]);
        xr1 = bf2f(gxl16[0][gb][gj0+1]); xz1 = bf2f(gxl16[1][gb][gj0+1]); xn1 = bf2f(gxl16[2][gb][gj0+1]);
      }
      float r0 = sigmf(xr0 + bihs[gj0]      + gh[0][gb][gj0] + bhhs[gj0]);
      float z0 = sigmf(xz0 + bihs[32+gj0]   + gh[1][gb][gj0] + bhhs[32+gj0]);
      float n0 = tanhf(xn0 + bihs[64+gj0]   + r0*(gh[2][gb][gj0] + bhhs[64+gj0]));
      hv0 = (1.f - z0)*n0 + z0*hp0;
      float r1 = sigmf(xr1 + bihs[gj0+1]    + gh[0][gb][gj0+1] + bhhs[gj0+1]);
      float z1 = sigmf(xz1 + bihs[32+gj0+1] + gh[1][gb][gj0+1] + bhhs[32+gj0+1]);
      float n1 = tanhf(xn1 + bihs[64+gj0+1] + r1*(gh[2][gb][gj0+1] + bhhs[64+gj0+1]));
      hv1 = (1.f - z1)*n1 + z1*hp1;
      hp0 = hv0; hp1 = hv1;

      // publish h_new pair to next image (agent-scope -> LLC)
      u32* img2 = (u32*)(himg + ((size_t)dir*2 + ((t + 1) & 1)) * 32 * 512);
      pv = (u32)f2bf(hv0) | ((u32)f2bf(hv1) << 16);
      __hip_atomic_store(img2 + gb*256 + jb*16 + (tid & 15), pv,
                         __ATOMIC_RELAXED, __HIP_MEMORY_SCOPE_AGENT);
    }
    __syncthreads();   // (D) pre-barrier waitcnt drains ALL waves' publish stores

    if (tid == 0)
      __hip_atomic_store(myflag, (u32)(t + 1), __ATOMIC_RELEASE, __HIP_MEMORY_SCOPE_AGENT);

    // --- out store AFTER flag release (HBM write ack off the critical path) ---
    {
      size_t oi = (size_t)(gb*TT + tt)*1024 + dir*512 + jb*CPW + gj0;
      if (outf32) {
        f32x2 ov; ov.x = hv0; ov.y = hv1;
        __builtin_nontemporal_store(ov, (f32x2*)((float*)out + oi));
      } else {
        __builtin_nontemporal_store(pv, (u32*)((u16*)out + oi));
      }
    }
  }
}

// ---------------- host ----------------
extern "C" void kernel_launch(void* const* d_in, const int* in_sizes, int n_in,
                              void* d_out, int out_size, void* d_ws, size_t ws_size,
                              hipStream_t stream) {
  (void)in_sizes; (void)n_in; (void)out_size;
  const float* x    = (const float*)d_in[0];
  const float* wih0 = (const float*)d_in[1];
  const float* whh0 = (const float*)d_in[2];
  const float* bih0 = (const float*)d_in[3];
  const float* bhh0 = (const float*)d_in[4];
  const float* wih1 = (const float*)d_in[5];
  const float* whh1 = (const float*)d_in[6];
  const float* bih1 = (const float*)d_in[7];
  const float* bhh1 = (const float*)d_in[8];

  char* ws = (char*)d_ws;
  size_t off = 0;
  auto alloc = [&](size_t bytes) { size_t o = off; off += (bytes + 255) & ~(size_t)255; return o; };
  size_t off_xb   = alloc((size_t)MM * 512 * 2);       // x bf16
  size_t off_wih0 = alloc((size_t)3072 * 512 * 2);
  size_t off_wih1 = alloc((size_t)3072 * 1024 * 2);
  size_t off_whh0 = alloc((size_t)3072 * 512 * 2);
  size_t off_whh1 = alloc((size_t)3072 * 512 * 2);
  size_t off_h0   = alloc((size_t)MM * 1024 * 2);      // layer-0 output bf16
  size_t off_sync = alloc(131072 + 4096);              // h images (128KB) + flags
  size_t off_gx   = off;                               // gx last
  int gxf32 = (ws_size >= off_gx + (size_t)MM * NG * 4) ? 1 : 0;

  u16* xb    = (u16*)(ws + off_xb);
  u16* wih0b = (u16*)(ws + off_wih0);
  u16* wih1b = (u16*)(ws + off_wih1);
  u16* whh0b = (u16*)(ws + off_whh0);
  u16* whh1b = (u16*)(ws + off_whh1);
  u16* h0b   = (u16*)(ws + off_h0);
  u16* himg  = (u16*)(ws + off_sync);
  u32* flags = (u32*)(ws + off_sync + 131072);
  char* gx   = ws + off_gx;

  cvt_bf16<<<4096, 256, 0, stream>>>(x,    xb,    MM*512/8);
  cvt_bf16<<<768,  256, 0, stream>>>(wih0, wih0b, 3072*512/8);
  cvt_bf16<<<1536, 256, 0, stream>>>(wih1, wih1b, 3072*1024/8);
  cvt_bf16<<<768,  256, 0, stream>>>(whh0, whh0b, 3072*512/8);
  cvt_bf16<<<768,  256, 0, stream>>>(whh1, whh1b, 3072*512/8);

  dim3 ggrid(NG/128, MM/128);   // (24, 128)

  // layer 0
  gemm_gx<<<ggrid, 256, 0, stream>>>(xb, wih0b, gx, 512, gxf32);
  (void)hipMemsetAsync(ws + off_sync, 0, 131072 + 4096, stream);
  bigru_rec<<<32, 512, 0, stream>>>(gx, whh0b, bih0, bhh0, (char*)h0b, himg, flags, gxf32, 0);

  // layer 1
  gemm_gx<<<ggrid, 256, 0, stream>>>(h0b, wih1b, gx, 1024, gxf32);
  (void)hipMemsetAsync(ws + off_sync, 0, 131072 + 4096, stream);
  bigru_rec<<<32, 512, 0, stream>>>(gx, whh1b, bih1, bhh1, (char*)d_out, himg, flags, gxf32, 1);
}